// Round 2
// baseline (241.378 us; speedup 1.0000x reference)
//
#include <hip/hip_runtime.h>

#define NT 16384
#define NH 2048
#define NE 64
#define TOPK 8

#define TB 32                 // tokens per block
#define KSTEPS 64             // 2048 / 32
#define KQ 4                  // K-split ways
#define KSW (KSTEPS / KQ)     // 16 k-steps per wave

// output layout (floats)
#define LOFF 0
#define WOFF (NT * NE)
#define IOFF (WOFF + NT * TOPK)
#define MOFF (IOFF + NT * TOPK)

typedef __attribute__((ext_vector_type(8))) short short8;
typedef __attribute__((ext_vector_type(4))) float floatx4;

union FragU { uint4 u; short8 s; };

// exact triple split of (a,b) into 3 packed bf16 words (truncation; residual 2^-24)
__device__ __forceinline__ unsigned pack3(float a, float b, unsigned& w1, unsigned& w2) {
    unsigned au = __float_as_uint(a), bu = __float_as_uint(b);
    unsigned ah0 = au & 0xFFFF0000u, bh0 = bu & 0xFFFF0000u;
    float ra = a - __uint_as_float(ah0);
    float rb = b - __uint_as_float(bh0);
    unsigned ar = __float_as_uint(ra), br = __float_as_uint(rb);
    unsigned ah1 = ar & 0xFFFF0000u, bh1 = br & 0xFFFF0000u;
    float sa = ra - __uint_as_float(ah1);
    float sb = rb - __uint_as_float(bh1);
    w1 = bh1 | (ah1 >> 16);
    w2 = (__float_as_uint(sb) & 0xFFFF0000u) | (__float_as_uint(sa) >> 16);
    return bh0 | (ah0 >> 16);
}

// ---------------------------------------------------------------------------
// Kernel 1: convert W_gate [64 x 2048] f32 -> 3 bf16 planes in B-fragment
// order. Record (t, g, p) = 1KB: lane l holds W_split_p[e = g*16 + (l&15)]
// [k = t*32 + (l>>4)*8 .. +7] as 8 bf16. Total 768 KB, L2-resident.
// ---------------------------------------------------------------------------
__global__ __launch_bounds__(64)
void wconv_kernel(const float* __restrict__ Wg, uint4* __restrict__ wsp) {
    const int b = blockIdx.x;            // 0..255
    const int t = b >> 2, g = b & 3;
    const int l = threadIdx.x;
    const int e  = g * 16 + (l & 15);
    const int k0 = t * 32 + (l >> 4) * 8;
    const float* src = Wg + (size_t)e * NH + k0;
    float4 w0 = *(const float4*)src;
    float4 w1 = *(const float4*)(src + 4);
    unsigned u1[4], u2[4];
    uint4 p0;
    p0.x = pack3(w0.x, w0.y, u1[0], u2[0]);
    p0.y = pack3(w0.z, w0.w, u1[1], u2[1]);
    p0.z = pack3(w1.x, w1.y, u1[2], u2[2]);
    p0.w = pack3(w1.z, w1.w, u1[3], u2[3]);
    uint4* dst = wsp + (size_t)((t * 4 + g) * 3) * 64 + l;
    dst[0]   = p0;
    dst[64]  = make_uint4(u1[0], u1[1], u1[2], u1[3]);
    dst[128] = make_uint4(u2[0], u2[1], u2[2], u2[3]);
}

// ---------------------------------------------------------------------------
// Kernel 2: main. 512 blocks x 512 threads (8 waves) = 16 waves/CU (4/SIMD).
// Wave w: kh = w&3 (K-quarter), th = w>>2 (token half). Each wave computes a
// 16-token x 64-expert partial over 512 k's: A-frags straight from global X
// (pack3 in registers), B-frags from the preconverted table (the two th-waves
// of a kh share identical B records -> L1 hits). NO LDS / NO barriers in the
// K-loop; LDS only for the 4-way k-reduction + logits tile.
// ---------------------------------------------------------------------------
__global__ __launch_bounds__(512, 4)
void router_kernel(const float* __restrict__ X, const uint4* __restrict__ wsp,
                   const float* __restrict__ bg, float* __restrict__ out) {
    __shared__ __align__(16) float P[KQ][TB][68];   // 34.8 KB partials
    __shared__ __align__(16) float Ls[TB][68];      //  8.7 KB logits

    const int tid = threadIdx.x;
    const int w   = tid >> 6;
    const int kh  = w & 3;               // K-quarter
    const int th  = w >> 2;              // token half
    const int l   = tid & 63;
    const int lr  = l & 15, lq = l >> 4;
    const int tbase = blockIdx.x * TB;

    floatx4 acc[4];
#pragma unroll
    for (int g = 0; g < 4; g++) acc[g] = (floatx4)0.0f;

    // A: lane -> (token row, 8 contiguous k) within my 16-token tile
    const float* xp0 = X + (size_t)(tbase + th * 16 + lr) * NH + kh * (KSW * 32) + lq * 8;
    // B: fragment records for this wave's K-range
    const uint4* wp = wsp + (size_t)(kh * KSW) * 12 * 64 + l;

    // initial A preload (issue before the mask-zero stores)
    float4 a0lo = *(const float4*)xp0;
    float4 a0hi = *(const float4*)(xp0 + 4);

    // ---- zero this block's mask slab (overlaps with K-loop loads) ----
    {
        float4 z = make_float4(0.f, 0.f, 0.f, 0.f);
#pragma unroll
        for (int m = 0; m < 8; m++) {
            int f2  = tid + 512 * m;          // 0..4095 float4s
            int seg = f2 >> 3;                // (e*8+kk) 0..511
            int off = (f2 & 7) << 2;          // 0..28
            *(float4*)(out + MOFF + (size_t)seg * NT + tbase + off) = z;
        }
    }

    // ---- K-loop: no LDS, no barriers ----
#pragma unroll 2
    for (int t = 0; t < KSW; t++) {
        // B-fragment loads first (L2 latency hides under pack3)
        FragU b[4][3];
        const uint4* wt = wp + t * 768;
#pragma unroll
        for (int g = 0; g < 4; g++)
#pragma unroll
            for (int p = 0; p < 3; p++)
                b[g][p].u = wt[(g * 3 + p) * 64];

        // pack current A into 3-plane fragments
        FragU af[3];
        {
            unsigned u1[4], u2[4];
            uint4 q;
            q.x = pack3(a0lo.x, a0lo.y, u1[0], u2[0]);
            q.y = pack3(a0lo.z, a0lo.w, u1[1], u2[1]);
            q.z = pack3(a0hi.x, a0hi.y, u1[2], u2[2]);
            q.w = pack3(a0hi.z, a0hi.w, u1[3], u2[3]);
            af[0].u = q;
            af[1].u = make_uint4(u1[0], u1[1], u1[2], u1[3]);
            af[2].u = make_uint4(u2[0], u2[1], u2[2], u2[3]);
        }

        // prefetch next A chunk (HBM latency hides under the MFMAs)
        if (t + 1 < KSW) {
            const float* nx0 = xp0 + (t + 1) * 32;
            a0lo = *(const float4*)nx0;
            a0hi = *(const float4*)(nx0 + 4);
        }

        // MFMAs: 4 expert-groups x 6 split-products
        __builtin_amdgcn_s_setprio(1);
#pragma unroll
        for (int g = 0; g < 4; g++) {
            acc[g] = __builtin_amdgcn_mfma_f32_16x16x32_bf16(af[0].s, b[g][0].s, acc[g], 0, 0, 0);
            acc[g] = __builtin_amdgcn_mfma_f32_16x16x32_bf16(af[0].s, b[g][1].s, acc[g], 0, 0, 0);
            acc[g] = __builtin_amdgcn_mfma_f32_16x16x32_bf16(af[1].s, b[g][0].s, acc[g], 0, 0, 0);
            acc[g] = __builtin_amdgcn_mfma_f32_16x16x32_bf16(af[1].s, b[g][1].s, acc[g], 0, 0, 0);
            acc[g] = __builtin_amdgcn_mfma_f32_16x16x32_bf16(af[0].s, b[g][2].s, acc[g], 0, 0, 0);
            acc[g] = __builtin_amdgcn_mfma_f32_16x16x32_bf16(af[2].s, b[g][0].s, acc[g], 0, 0, 0);
        }
        __builtin_amdgcn_s_setprio(0);
    }

    // ---- dump partials ----
#pragma unroll
    for (int g = 0; g < 4; g++)
#pragma unroll
        for (int r = 0; r < 4; r++)
            P[kh][th * 16 + lq * 4 + r][g * 16 + lr] = acc[g][r];
    __syncthreads();

    // ---- 4-way reduce + bias -> Ls + coalesced logits write ----
    {
        int f4  = tid;                       // 0..511 float4s
        int tok = f4 >> 4;
        int e4  = (f4 & 15) << 2;
        float4 s0 = *(float4*)&P[0][tok][e4];
        float4 s1 = *(float4*)&P[1][tok][e4];
        float4 s2 = *(float4*)&P[2][tok][e4];
        float4 s3 = *(float4*)&P[3][tok][e4];
        float4 bb = *(const float4*)(bg + e4);
        float4 v;
        v.x = s0.x + s1.x + s2.x + s3.x + bb.x;
        v.y = s0.y + s1.y + s2.y + s3.y + bb.y;
        v.z = s0.z + s1.z + s2.z + s3.z + bb.z;
        v.w = s0.w + s1.w + s2.w + s3.w + bb.w;
        *(float4*)&Ls[tok][e4] = v;
        *(float4*)(out + LOFF + (size_t)tbase * NE + (size_t)f4 * 4) = v;
    }
    __syncthreads();

    // ---- wave-parallel top-8: 8 lanes per token (first 4 waves) ----
    if (tid < 256) {
        const int tok = tid >> 3;
        const int el  = tid & 7;             // this lane owns experts el*8..el*8+7
        float4 va = *(float4*)&Ls[tok][el * 8];
        float4 vb = *(float4*)&Ls[tok][el * 8 + 4];
        float v[8] = {va.x, va.y, va.z, va.w, vb.x, vb.y, vb.z, vb.w};

        unsigned msk = 0;
        float m0 = 0.f, ssum = 0.f, myv = 0.f;
        int myi = 0;
#pragma unroll
        for (int r = 0; r < 8; r++) {
            float bv = -3.0e38f; int bi = 64;
#pragma unroll
            for (int j = 0; j < 8; j++) {
                bool better = (((msk >> j) & 1u) == 0u) && (v[j] > bv);  // strict >: lowest idx wins
                bv = better ? v[j] : bv;
                bi = better ? (el * 8 + j) : bi;
            }
#pragma unroll
            for (int s2 = 1; s2 < 8; s2 <<= 1) {
                float ov = __shfl_xor(bv, s2);
                int   oi = __shfl_xor(bi, s2);
                bool take = (ov > bv) || (ov == bv && oi < bi);
                bv = take ? ov : bv;
                bi = take ? oi : bi;
            }
            if ((bi >> 3) == el) msk |= (1u << (bi & 7));
            if (r == 0) m0 = bv;
            ssum += __expf(bv - m0);
            if (r == el) { myv = bv; myi = bi; }   // static r vs runtime el -> cndmask
        }
        float wgt = __expf(myv - m0) / ssum;
        size_t gt = (size_t)(tbase + tok);
        out[WOFF + gt * TOPK + el] = wgt;
        out[IOFF + gt * TOPK + el] = (float)myi;
        out[MOFF + (size_t)myi * (TOPK * NT) + (size_t)el * NT + gt] = 1.0f;
    }
}

extern "C" void kernel_launch(void* const* d_in, const int* in_sizes, int n_in,
                              void* d_out, int out_size, void* d_ws, size_t ws_size,
                              hipStream_t stream) {
    const float* X  = (const float*)d_in[0];
    const float* Wg = (const float*)d_in[1];
    const float* bg = (const float*)d_in[2];
    float* out = (float*)d_out;
    uint4* wsp = (uint4*)d_ws;   // needs 768 KB

    hipLaunchKernelGGL(wconv_kernel, dim3(KSTEPS * 4), dim3(64), 0, stream, Wg, wsp);
    hipLaunchKernelGGL(router_kernel, dim3(NT / TB), dim3(512), 0, stream,
                       X, (const uint4*)wsp, bg, out);
}

// Round 3
// 232.280 us; speedup vs baseline: 1.0392x; 1.0392x over previous
//
#include <hip/hip_runtime.h>

#define NT 16384
#define NH 2048
#define NE 64
#define TOPK 8

#define TB 32                 // tokens per block
#define NSTEP 64              // K steps of 32
#define DEPTH 4               // pipeline depth (slabs in flight)

// output layout (floats)
#define LOFF 0
#define WOFF (NT * NE)
#define IOFF (WOFF + NT * TOPK)
#define MOFF (IOFF + NT * TOPK)

typedef __attribute__((ext_vector_type(8))) short short8;
typedef __attribute__((ext_vector_type(4))) float floatx4;

union FragU { uint4 u; short8 s; };

#define WAITVM(n) asm volatile("s_waitcnt vmcnt(" #n ")" ::: "memory")

__device__ __forceinline__ void glds16(const void* g, void* l) {
    __builtin_amdgcn_global_load_lds(
        (const __attribute__((address_space(1))) unsigned int*)g,
        (__attribute__((address_space(3))) unsigned int*)l, 16, 0, 0);
}

// exact triple split of (a,b) into 3 packed bf16 words (truncation; residual 2^-24)
__device__ __forceinline__ unsigned pack3(float a, float b, unsigned& w1, unsigned& w2) {
    unsigned au = __float_as_uint(a), bu = __float_as_uint(b);
    unsigned ah0 = au & 0xFFFF0000u, bh0 = bu & 0xFFFF0000u;
    float ra = a - __uint_as_float(ah0);
    float rb = b - __uint_as_float(bh0);
    unsigned ar = __float_as_uint(ra), br = __float_as_uint(rb);
    unsigned ah1 = ar & 0xFFFF0000u, bh1 = br & 0xFFFF0000u;
    float sa = ra - __uint_as_float(ah1);
    float sb = rb - __uint_as_float(bh1);
    w1 = bh1 | (ah1 >> 16);
    w2 = (__float_as_uint(sb) & 0xFFFF0000u) | (__float_as_uint(sa) >> 16);
    return bh0 | (ah0 >> 16);
}

// ---------------------------------------------------------------------------
// prep: (a) zero the expert_mask (33.5 MB) with contiguous fill-style stores;
// (b) convert W_gate -> 3-plane bf16 B-fragment table in d_ws (768 KB,
// L2-resident). Record (t, g, p) = 1KB: lane l holds plane p of
// W[e = g*16 + (l&15)][k = t*32 + (l>>4)*8 .. +7].
// ---------------------------------------------------------------------------
__global__ __launch_bounds__(256)
void prep_kernel(const float* __restrict__ Wg, uint4* __restrict__ wsp,
                 float* __restrict__ out) {
    const int b = blockIdx.x;            // 0..255
    const int tid = threadIdx.x;

    // mask zero: 2,097,152 float4s / 256 blocks = 8192 per block
    float4 z = make_float4(0.f, 0.f, 0.f, 0.f);
    float4* mp = (float4*)(out + MOFF) + (size_t)b * 8192 + tid;
#pragma unroll
    for (int it = 0; it < 32; it++) mp[it * 256] = z;

    if (tid < 64) {
        const int t = b >> 2, g = b & 3;
        const int l = tid;
        const int e  = g * 16 + (l & 15);
        const int k0 = t * 32 + (l >> 4) * 8;
        const float* src = Wg + (size_t)e * NH + k0;
        float4 w0 = *(const float4*)src;
        float4 w1 = *(const float4*)(src + 4);
        unsigned u1[4], u2[4];
        uint4 p0;
        p0.x = pack3(w0.x, w0.y, u1[0], u2[0]);
        p0.y = pack3(w0.z, w0.w, u1[1], u2[1]);
        p0.z = pack3(w1.x, w1.y, u1[2], u2[2]);
        p0.w = pack3(w1.z, w1.w, u1[3], u2[3]);
        uint4* dst = wsp + (size_t)((t * 4 + g) * 3) * 64 + l;
        dst[0]   = p0;
        dst[64]  = make_uint4(u1[0], u1[1], u1[2], u1[3]);
        dst[128] = make_uint4(u2[0], u2[1], u2[2], u2[3]);
    }
}

// ---------------------------------------------------------------------------
// router: 512 blocks x 256 threads (4 waves) = 2 blocks/CU. Wave (th, eh) =
// 16-token tile x 32-expert half, full K. Per k-step (32 k): slab = X tile
// (4 KB, granule-XOR swizzled) + B records (12 KB, linear), staged via
// global_load_lds into a DEPTH=4 circular LDS pipeline with counted vmcnt
// (never 0 in the main loop) and raw s_barrier. pack3 of A in registers.
// ---------------------------------------------------------------------------
__global__ __launch_bounds__(256, 2)
void router_kernel(const float* __restrict__ X, const uint4* __restrict__ wsp,
                   const float* __restrict__ bg, float* __restrict__ out) {
    __shared__ uint4 SB[DEPTH][1024];      // 64 KB: per slab [0..255]=X, [256..1023]=B
    __shared__ float Ls[TB][68];           // 8.7 KB logits

    const int tid = threadIdx.x;
    const int wv  = tid >> 6;
    const int l   = tid & 63;
    const int th  = wv >> 1;               // token tile (16 rows)
    const int eh  = wv & 1;                // expert half (32 experts)
    const int lr  = l & 15, lq = l >> 4;
    const int tbase = blockIdx.x * TB;

    floatx4 acc[2];
    acc[0] = (floatx4)0.0f;
    acc[1] = (floatx4)0.0f;

    // staging geometry
    const int srow = tid >> 3, sg = tid & 7;
    // pre-swizzled global source: LDS slot (srow, sg) receives global granule sg^(srow&7)
    const float* xsrc0 = X + (size_t)(tbase + srow) * NH + ((sg ^ (srow & 7)) * 4);
    const uint4* wsrc0 = wsp + (tid & 63);

#define STAGE(t_, s_) do { \
    glds16(xsrc0 + (t_) * 32, &SB[s_][tid]); \
    glds16(wsrc0 + ((size_t)(t_) * 12 + (0 * 4 + wv)) * 64, &SB[s_][256 + (0 * 4 + wv) * 64 + l]); \
    glds16(wsrc0 + ((size_t)(t_) * 12 + (1 * 4 + wv)) * 64, &SB[s_][256 + (1 * 4 + wv) * 64 + l]); \
    glds16(wsrc0 + ((size_t)(t_) * 12 + (2 * 4 + wv)) * 64, &SB[s_][256 + (2 * 4 + wv) * 64 + l]); \
} while (0)

#define MFMA6(accv, A0, A1, A2, B0, B1, B2) do { \
    accv = __builtin_amdgcn_mfma_f32_16x16x32_bf16(A0, B0, accv, 0, 0, 0); \
    accv = __builtin_amdgcn_mfma_f32_16x16x32_bf16(A0, B1, accv, 0, 0, 0); \
    accv = __builtin_amdgcn_mfma_f32_16x16x32_bf16(A1, B0, accv, 0, 0, 0); \
    accv = __builtin_amdgcn_mfma_f32_16x16x32_bf16(A1, B1, accv, 0, 0, 0); \
    accv = __builtin_amdgcn_mfma_f32_16x16x32_bf16(A0, B2, accv, 0, 0, 0); \
    accv = __builtin_amdgcn_mfma_f32_16x16x32_bf16(A2, B0, accv, 0, 0, 0); \
} while (0)

#define CONSUME(s_) do { \
    const int arow_ = th * 16 + lr; \
    const float4 lo_ = *(const float4*)&SB[s_][arow_ * 8 + ((2 * lq) ^ (arow_ & 7))]; \
    const float4 hi_ = *(const float4*)&SB[s_][arow_ * 8 + ((2 * lq + 1) ^ (arow_ & 7))]; \
    FragU b00, b01, b02, b10, b11, b12; \
    b00.u = SB[s_][256 + ((eh * 2 + 0) * 3 + 0) * 64 + l]; \
    b01.u = SB[s_][256 + ((eh * 2 + 0) * 3 + 1) * 64 + l]; \
    b02.u = SB[s_][256 + ((eh * 2 + 0) * 3 + 2) * 64 + l]; \
    b10.u = SB[s_][256 + ((eh * 2 + 1) * 3 + 0) * 64 + l]; \
    b11.u = SB[s_][256 + ((eh * 2 + 1) * 3 + 1) * 64 + l]; \
    b12.u = SB[s_][256 + ((eh * 2 + 1) * 3 + 2) * 64 + l]; \
    FragU af0_, af1_, af2_; \
    { unsigned u1_[4], u2_[4]; uint4 q_; \
      q_.x = pack3(lo_.x, lo_.y, u1_[0], u2_[0]); \
      q_.y = pack3(lo_.z, lo_.w, u1_[1], u2_[1]); \
      q_.z = pack3(hi_.x, hi_.y, u1_[2], u2_[2]); \
      q_.w = pack3(hi_.z, hi_.w, u1_[3], u2_[3]); \
      af0_.u = q_; \
      af1_.u = make_uint4(u1_[0], u1_[1], u1_[2], u1_[3]); \
      af2_.u = make_uint4(u2_[0], u2_[1], u2_[2], u2_[3]); } \
    MFMA6(acc[0], af0_.s, af1_.s, af2_.s, b00.s, b01.s, b02.s); \
    MFMA6(acc[1], af0_.s, af1_.s, af2_.s, b10.s, b11.s, b12.s); \
} while (0)

    // prologue: fill the pipeline
    STAGE(0, 0); STAGE(1, 1); STAGE(2, 2); STAGE(3, 3);

#pragma unroll 4
    for (int t = 0; t < NSTEP - DEPTH; t++) {
        const int s = t & (DEPTH - 1);
        WAITVM(12);                              // oldest slab landed (own loads)
        __builtin_amdgcn_s_barrier();            // everyone's loads for slab t landed
        CONSUME(s);
        asm volatile("s_waitcnt lgkmcnt(0)" ::: "memory");
        __builtin_amdgcn_s_barrier();            // all waves done reading slot s
        STAGE(t + DEPTH, s);                     // refill freed slot
    }
    // tail: drain the pipeline with decreasing counts
    WAITVM(12); __builtin_amdgcn_s_barrier(); CONSUME(0);
    WAITVM(8);  __builtin_amdgcn_s_barrier(); CONSUME(1);
    WAITVM(4);  __builtin_amdgcn_s_barrier(); CONSUME(2);
    WAITVM(0);  __builtin_amdgcn_s_barrier(); CONSUME(3);

    // ---- bias + logits tile ----
    const float bias0 = bg[eh * 32 + lr];
    const float bias1 = bg[eh * 32 + 16 + lr];
#pragma unroll
    for (int rr = 0; rr < 4; rr++) {
        Ls[th * 16 + lq * 4 + rr][eh * 32 + lr]      = acc[0][rr] + bias0;
        Ls[th * 16 + lq * 4 + rr][eh * 32 + 16 + lr] = acc[1][rr] + bias1;
    }
    __syncthreads();

    // ---- coalesced logits write ----
#pragma unroll
    for (int v = 0; v < 2; v++) {
        int f4  = v * 256 + tid;                 // 0..511 float4s
        int tok = f4 >> 4;
        int e4  = (f4 & 15) << 2;
        float4 o = *(const float4*)&Ls[tok][e4];
        *(float4*)(out + LOFF + (size_t)tbase * NE + (size_t)f4 * 4) = o;
    }

    // ---- wave-parallel top-8: 8 lanes per token ----
    const int tok = tid >> 3;
    const int el  = tid & 7;                     // lane owns experts el*8..el*8+7
    float4 va = *(const float4*)&Ls[tok][el * 8];
    float4 vb = *(const float4*)&Ls[tok][el * 8 + 4];
    float v[8] = {va.x, va.y, va.z, va.w, vb.x, vb.y, vb.z, vb.w};

    unsigned msk = 0;
    float m0 = 0.f, ssum = 0.f, myv = 0.f;
    int myi = 0;
#pragma unroll
    for (int r = 0; r < 8; r++) {
        float bv = -3.0e38f; int bi = 64;
#pragma unroll
        for (int j = 0; j < 8; j++) {
            bool better = (((msk >> j) & 1u) == 0u) && (v[j] > bv);  // strict >: lowest idx wins
            bv = better ? v[j] : bv;
            bi = better ? (el * 8 + j) : bi;
        }
#pragma unroll
        for (int s2 = 1; s2 < 8; s2 <<= 1) {
            float ov = __shfl_xor(bv, s2);
            int   oi = __shfl_xor(bi, s2);
            bool take = (ov > bv) || (ov == bv && oi < bi);
            bv = take ? ov : bv;
            bi = take ? oi : bi;
        }
        if ((bi >> 3) == el) msk |= (1u << (bi & 7));
        if (r == 0) m0 = bv;
        ssum += __expf(bv - m0);
        if (r == el) { myv = bv; myi = bi; }     // static r vs runtime el -> cndmask
    }
    float wgt = __expf(myv - m0) / ssum;
    size_t gt = (size_t)(tbase + tok);
    out[WOFF + gt * TOPK + el] = wgt;
    out[IOFF + gt * TOPK + el] = (float)myi;
    out[MOFF + (size_t)myi * (TOPK * NT) + (size_t)el * NT + gt] = 1.0f;
}

extern "C" void kernel_launch(void* const* d_in, const int* in_sizes, int n_in,
                              void* d_out, int out_size, void* d_ws, size_t ws_size,
                              hipStream_t stream) {
    const float* X  = (const float*)d_in[0];
    const float* Wg = (const float*)d_in[1];
    const float* bg = (const float*)d_in[2];
    float* out = (float*)d_out;
    uint4* wsp = (uint4*)d_ws;   // needs 768 KB

    hipLaunchKernelGGL(prep_kernel, dim3(256), dim3(256), 0, stream, Wg, wsp, out);
    hipLaunchKernelGGL(router_kernel, dim3(NT / TB), dim3(256), 0, stream,
                       X, (const uint4*)wsp, bg, out);
}

// Round 4
// 231.273 us; speedup vs baseline: 1.0437x; 1.0044x over previous
//
#include <hip/hip_runtime.h>

#define NT 16384
#define NH 2048
#define NE 64
#define TOPK 8

#define TB 32                 // tokens per block
#define NSTEP 64              // K steps of 32 floats
#define CSTEP 8               // k-steps per chunk (1 KB per row per chunk)
#define NCHUNK (NSTEP / CSTEP)

// output layout (floats)
#define LOFF 0
#define WOFF (NT * NE)
#define IOFF (WOFF + NT * TOPK)
#define MOFF (IOFF + NT * TOPK)

typedef __attribute__((ext_vector_type(8))) short short8;
typedef __attribute__((ext_vector_type(4))) float floatx4;

union FragU { uint4 u; short8 s; };

#define WAITVM(n) asm volatile("s_waitcnt vmcnt(" #n ")" ::: "memory")
#define LGKM0     asm volatile("s_waitcnt lgkmcnt(0)" ::: "memory")

__device__ __forceinline__ void glds16(const void* g, void* l) {
    __builtin_amdgcn_global_load_lds(
        (const __attribute__((address_space(1))) unsigned int*)g,
        (__attribute__((address_space(3))) unsigned int*)l, 16, 0, 0);
}

// exact triple split of (a,b) into 3 packed bf16 words (truncation; residual 2^-24)
__device__ __forceinline__ unsigned pack3(float a, float b, unsigned& w1, unsigned& w2) {
    unsigned au = __float_as_uint(a), bu = __float_as_uint(b);
    unsigned ah0 = au & 0xFFFF0000u, bh0 = bu & 0xFFFF0000u;
    float ra = a - __uint_as_float(ah0);
    float rb = b - __uint_as_float(bh0);
    unsigned ar = __float_as_uint(ra), br = __float_as_uint(rb);
    unsigned ah1 = ar & 0xFFFF0000u, bh1 = br & 0xFFFF0000u;
    float sa = ra - __uint_as_float(ah1);
    float sb = rb - __uint_as_float(bh1);
    w1 = bh1 | (ah1 >> 16);
    w2 = (__float_as_uint(sb) & 0xFFFF0000u) | (__float_as_uint(sa) >> 16);
    return bh0 | (ah0 >> 16);
}

// ---------------------------------------------------------------------------
// prep: (a) zero the expert_mask (33.5 MB) with contiguous stores;
// (b) convert W_gate -> 3-plane bf16 B-fragment table in d_ws (768 KB,
// L2-resident). Record (t, g, p) = 1KB: lane l holds plane p of
// W[e = g*16 + (l&15)][k = t*32 + (l>>4)*8 .. +7].
// ---------------------------------------------------------------------------
__global__ __launch_bounds__(256)
void prep_kernel(const float* __restrict__ Wg, uint4* __restrict__ wsp,
                 float* __restrict__ out) {
    const int b = blockIdx.x;            // 0..255
    const int tid = threadIdx.x;

    float4 z = make_float4(0.f, 0.f, 0.f, 0.f);
    float4* mp = (float4*)(out + MOFF) + (size_t)b * 8192 + tid;
#pragma unroll
    for (int it = 0; it < 32; it++) mp[it * 256] = z;

    if (tid < 64) {
        const int t = b >> 2, g = b & 3;
        const int l = tid;
        const int e  = g * 16 + (l & 15);
        const int k0 = t * 32 + (l >> 4) * 8;
        const float* src = Wg + (size_t)e * NH + k0;
        float4 w0 = *(const float4*)src;
        float4 w1 = *(const float4*)(src + 4);
        unsigned u1[4], u2[4];
        uint4 p0;
        p0.x = pack3(w0.x, w0.y, u1[0], u2[0]);
        p0.y = pack3(w0.z, w0.w, u1[1], u2[1]);
        p0.z = pack3(w1.x, w1.y, u1[2], u2[2]);
        p0.w = pack3(w1.z, w1.w, u1[3], u2[3]);
        uint4* dst = wsp + (size_t)((t * 4 + g) * 3) * 64 + l;
        dst[0]   = p0;
        dst[64]  = make_uint4(u1[0], u1[1], u1[2], u1[3]);
        dst[128] = make_uint4(u2[0], u2[1], u2[2], u2[3]);
    }
}

// ---------------------------------------------------------------------------
// router: 512 blocks x 256 threads (4 waves), 2 blocks/CU. Wave (th, eh) =
// 16-token tile x 32-expert half, full K. X staged in 8-step (1 KB/row)
// chunks: ONE global_load_lds per ROW -> lanes cover 1 KB contiguous
// (8 sequential cache lines / instr; DRAM sees 1-KB runs). Lane->granule
// XOR (l^j) pre-applied on the GLOBAL addr (same 1-KB region) so LDS reads
// are bank-spread. Double-buffered, counted vmcnt, raw barriers. B = 1-KB
// coalesced register loads from the L2-hot table.
// ---------------------------------------------------------------------------
__global__ __launch_bounds__(256, 2)
void router_kernel(const float* __restrict__ X, const uint4* __restrict__ wsp,
                   const float* __restrict__ bg, float* __restrict__ out) {
    __shared__ float SB[2][TB][256];       // 64 KB: 2 slots x 32 rows x 1 KB
    __shared__ float Ls[TB][68];           // 8.7 KB logits

    const int tid = threadIdx.x;
    const int wv  = tid >> 6;
    const int l   = tid & 63;
    const int th  = wv >> 1;               // token tile (16 rows)
    const int eh  = wv & 1;                // expert half (32 experts)
    const int lr  = l & 15, lq = l >> 4;
    const int lr7 = lr & 7;
    const int tbase = blockIdx.x * TB;

    floatx4 acc[2];
    acc[0] = (floatx4)0.0f;
    acc[1] = (floatx4)0.0f;

    // staging: wave wv owns rows wv*8 .. wv*8+7; one glds per row
    const float* xsrc = X + (size_t)(tbase + wv * 8) * NH;
    const uint4* wb   = wsp + l;

#define STAGE(c_, s_) do { \
    _Pragma("unroll") \
    for (int j_ = 0; j_ < 8; j_++) \
        glds16(xsrc + (size_t)j_ * NH + (c_) * 256 + ((l ^ j_) << 2), \
               &SB[s_][wv * 8 + j_][0]); \
} while (0)

#define MFMA6(accv, A0, A1, A2, B0, B1, B2) do { \
    accv = __builtin_amdgcn_mfma_f32_16x16x32_bf16(A0, B0, accv, 0, 0, 0); \
    accv = __builtin_amdgcn_mfma_f32_16x16x32_bf16(A0, B1, accv, 0, 0, 0); \
    accv = __builtin_amdgcn_mfma_f32_16x16x32_bf16(A1, B0, accv, 0, 0, 0); \
    accv = __builtin_amdgcn_mfma_f32_16x16x32_bf16(A1, B1, accv, 0, 0, 0); \
    accv = __builtin_amdgcn_mfma_f32_16x16x32_bf16(A0, B2, accv, 0, 0, 0); \
    accv = __builtin_amdgcn_mfma_f32_16x16x32_bf16(A2, B0, accv, 0, 0, 0); \
} while (0)

#define KSTEP(s_, sg_, j_) do { \
    const float* ar_ = &SB[s_][th * 16 + lr][0]; \
    float4 lo_ = *(const float4*)(ar_ + ((((j_) * 8 + lq * 2 + 0) ^ lr7) << 2)); \
    float4 hi_ = *(const float4*)(ar_ + ((((j_) * 8 + lq * 2 + 1) ^ lr7) << 2)); \
    const uint4* wt_ = wb + ((size_t)(sg_) * 12 + eh * 6) * 64; \
    FragU b00, b01, b02, b10, b11, b12; \
    b00.u = wt_[0];   b01.u = wt_[64];  b02.u = wt_[128]; \
    b10.u = wt_[192]; b11.u = wt_[256]; b12.u = wt_[320]; \
    FragU a0_, a1_, a2_; \
    { unsigned u1_[4], u2_[4]; uint4 q_; \
      q_.x = pack3(lo_.x, lo_.y, u1_[0], u2_[0]); \
      q_.y = pack3(lo_.z, lo_.w, u1_[1], u2_[1]); \
      q_.z = pack3(hi_.x, hi_.y, u1_[2], u2_[2]); \
      q_.w = pack3(hi_.z, hi_.w, u1_[3], u2_[3]); \
      a0_.u = q_; \
      a1_.u = make_uint4(u1_[0], u1_[1], u1_[2], u1_[3]); \
      a2_.u = make_uint4(u2_[0], u2_[1], u2_[2], u2_[3]); } \
    __builtin_amdgcn_s_setprio(1); \
    MFMA6(acc[0], a0_.s, a1_.s, a2_.s, b00.s, b01.s, b02.s); \
    MFMA6(acc[1], a0_.s, a1_.s, a2_.s, b10.s, b11.s, b12.s); \
    __builtin_amdgcn_s_setprio(0); \
} while (0)

    // prologue: fill both slots
    STAGE(0, 0);
    STAGE(1, 1);

    // chunk 0 (peeled: only 8 ops issued after its stage)
    WAITVM(8);
    __builtin_amdgcn_s_barrier();
#pragma unroll
    for (int j = 0; j < 8; j++) KSTEP(0, j, j);
    LGKM0;
    __builtin_amdgcn_s_barrier();
    STAGE(2, 0);

#pragma unroll 1
    for (int c = 1; c < NCHUNK; c++) {
        const int slot = c & 1;
        WAITVM(40);                       // own chunk-c glds landed; next stays in flight
        __builtin_amdgcn_s_barrier();     // all waves' chunk-c rows landed
#pragma unroll
        for (int j = 0; j < 8; j++) KSTEP(slot, c * 8 + j, j);
        LGKM0;
        __builtin_amdgcn_s_barrier();     // all waves done reading this slot
        if (c < NCHUNK - 2) STAGE(c + 2, slot);
    }

    // ---- bias + logits tile ----
    const float b0 = bg[eh * 32 + lr];
    const float b1 = bg[eh * 32 + 16 + lr];
#pragma unroll
    for (int rr = 0; rr < 4; rr++) {
        Ls[th * 16 + lq * 4 + rr][eh * 32 + lr]      = acc[0][rr] + b0;
        Ls[th * 16 + lq * 4 + rr][eh * 32 + 16 + lr] = acc[1][rr] + b1;
    }
    __syncthreads();

    // ---- coalesced logits write ----
#pragma unroll
    for (int v = 0; v < 2; v++) {
        int f4  = v * 256 + tid;                 // 0..511 float4s
        int tok = f4 >> 4;
        int e4  = (f4 & 15) << 2;
        float4 o = *(const float4*)&Ls[tok][e4];
        *(float4*)(out + LOFF + (size_t)tbase * NE + (size_t)f4 * 4) = o;
    }

    // ---- wave-parallel top-8: 8 lanes per token ----
    const int tok = tid >> 3;
    const int el  = tid & 7;                     // lane owns experts el*8..el*8+7
    float4 va = *(const float4*)&Ls[tok][el * 8];
    float4 vb = *(const float4*)&Ls[tok][el * 8 + 4];
    float v[8] = {va.x, va.y, va.z, va.w, vb.x, vb.y, vb.z, vb.w};

    unsigned msk = 0;
    float m0 = 0.f, ssum = 0.f, myv = 0.f;
    int myi = 0;
#pragma unroll
    for (int r = 0; r < 8; r++) {
        float bv = -3.0e38f; int bi = 64;
#pragma unroll
        for (int j = 0; j < 8; j++) {
            bool better = (((msk >> j) & 1u) == 0u) && (v[j] > bv);  // strict >: lowest idx wins
            bv = better ? v[j] : bv;
            bi = better ? (el * 8 + j) : bi;
        }
#pragma unroll
        for (int s2 = 1; s2 < 8; s2 <<= 1) {
            float ov = __shfl_xor(bv, s2);
            int   oi = __shfl_xor(bi, s2);
            bool take = (ov > bv) || (ov == bv && oi < bi);
            bv = take ? ov : bv;
            bi = take ? oi : bi;
        }
        if ((bi >> 3) == el) msk |= (1u << (bi & 7));
        if (r == 0) m0 = bv;
        ssum += __expf(bv - m0);
        if (r == el) { myv = bv; myi = bi; }     // static r vs runtime el -> cndmask
    }
    float wgt = __expf(myv - m0) / ssum;
    size_t gt = (size_t)(tbase + tok);
    out[WOFF + gt * TOPK + el] = wgt;
    out[IOFF + gt * TOPK + el] = (float)myi;
    out[MOFF + (size_t)myi * (TOPK * NT) + (size_t)el * NT + gt] = 1.0f;
}

extern "C" void kernel_launch(void* const* d_in, const int* in_sizes, int n_in,
                              void* d_out, int out_size, void* d_ws, size_t ws_size,
                              hipStream_t stream) {
    const float* X  = (const float*)d_in[0];
    const float* Wg = (const float*)d_in[1];
    const float* bg = (const float*)d_in[2];
    float* out = (float*)d_out;
    uint4* wsp = (uint4*)d_ws;   // needs 768 KB

    hipLaunchKernelGGL(prep_kernel, dim3(256), dim3(256), 0, stream, Wg, wsp, out);
    hipLaunchKernelGGL(router_kernel, dim3(NT / TB), dim3(256), 0, stream,
                       X, (const uint4*)wsp, bg, out);
}